// Round 7
// baseline (180.309 us; speedup 1.0000x reference)
//
#include <hip/hip_runtime.h>
#include <hip/hip_bf16.h>

typedef __bf16 bf16_t;
typedef __bf16 v8bf __attribute__((ext_vector_type(8)));
typedef float  v4f  __attribute__((ext_vector_type(4)));

#define MFMA16(a, b, c) __builtin_amdgcn_mfma_f32_16x16x32_bf16((a), (b), (c), 0, 0, 0)

#define GLDS16(g, l) __builtin_amdgcn_global_load_lds(                         \
    (const __attribute__((address_space(1))) void*)(g),                        \
    (__attribute__((address_space(3))) void*)(l), 16, 0, 0)

// counted-vmcnt sync primitives (attn only): raw barrier, no implicit drain
#define VMEMCNT(n) asm volatile("s_waitcnt vmcnt(" #n ")" ::: "memory")
#define SBAR()     __builtin_amdgcn_s_barrier()
#define SFENCE()   __builtin_amdgcn_sched_barrier(0)

#define B_SZ   2
#define SEQ    2048
#define DM     1024
#define NH     16
#define HD     64
#define M_TOT  4096

// 0.125 * log2(e): Q pre-scale so softmax uses exp2 with no multiply
#define QSCALE 0.18033688011112043f

// ---------------------------------------------------------------------------
// convert x fp32 -> bf16  (4M elems, 8/thread)
// ---------------------------------------------------------------------------
__global__ __launch_bounds__(256)
void conv_x_kernel(const float* __restrict__ src, bf16_t* __restrict__ dst)
{
    int i = (blockIdx.x * 256 + threadIdx.x) * 8;
    float4 a = *reinterpret_cast<const float4*>(src + i);
    float4 b = *reinterpret_cast<const float4*>(src + i + 4);
    union { bf16_t h[8]; int4 v; } u;
    u.h[0] = (bf16_t)a.x; u.h[1] = (bf16_t)a.y; u.h[2] = (bf16_t)a.z; u.h[3] = (bf16_t)a.w;
    u.h[4] = (bf16_t)b.x; u.h[5] = (bf16_t)b.y; u.h[6] = (bf16_t)b.z; u.h[7] = (bf16_t)b.w;
    *reinterpret_cast<int4*>(dst + i) = u.v;
}

// ---------------------------------------------------------------------------
// transpose+convert W fp32 [k][n] -> bf16 [n][k].  grid (32,32,4)
// ---------------------------------------------------------------------------
__global__ __launch_bounds__(256)
void conv_wt_kernel(const float* __restrict__ Wq, const float* __restrict__ Wk,
                    const float* __restrict__ Wv, const float* __restrict__ Wo,
                    bf16_t* __restrict__ WqkvT, bf16_t* __restrict__ WoT)
{
    __shared__ float t[32][33];
    const int z = blockIdx.z;
    const float* src = (z == 0) ? Wq : (z == 1) ? Wk : (z == 2) ? Wv : Wo;
    bf16_t* dst = (z < 3) ? (WqkvT + (size_t)z * 1048576) : WoT;
    const int tx = threadIdx.x & 31, ty = threadIdx.x >> 5;
    const int c0 = blockIdx.x * 32, r0 = blockIdx.y * 32;
#pragma unroll
    for (int i = 0; i < 4; ++i)
        t[ty + i * 8][tx] = src[(size_t)(r0 + ty + i * 8) * DM + c0 + tx];
    __syncthreads();
#pragma unroll
    for (int i = 0; i < 4; ++i)
        dst[(size_t)(c0 + ty + i * 8) * DM + r0 + tx] = (bf16_t)t[tx][ty + i * 8];
}

// ---------------------------------------------------------------------------
// Fused QKV GEMM.  r16: 128x128 SINGLE-buffered (m97 structure).
//   LDS 32KB -> 3 blocks/CU (grid 768 = exactly 3/CU, uniform); barrier
//   drain hidden by cross-block TLP (m97/m114 mechanism) instead of dbuf.
//   Loop: sync(drain) -> compute -> sync -> stage next.
// ---------------------------------------------------------------------------
__global__ __launch_bounds__(256)
void gemm_qkv_kernel(const bf16_t* __restrict__ A, const bf16_t* __restrict__ BT,
                     const float* __restrict__ b0, const float* __restrict__ b1,
                     const float* __restrict__ b2,
                     bf16_t* __restrict__ oQ, bf16_t* __restrict__ oK,
                     bf16_t* __restrict__ oV)
{
    __shared__ __align__(16) bf16_t As[128 * 64];   // 16 KB
    __shared__ __align__(16) bf16_t Bs[128 * 64];   // 16 KB

    const int tid  = threadIdx.x;
    const int lane = tid & 63;
    const int wave = tid >> 6;
    const int wm   = (wave >> 1) * 64;
    const int wn   = (wave & 1) * 64;
    const int quad = lane >> 4;
    const int l15  = lane & 15;
    const int l7   = l15 & 7;

    const int mat = blockIdx.x >> 3;
    const int n0  = (blockIdx.x & 7) * 128;
    const int m0  = blockIdx.y * 128;
    const bf16_t* Bmat = BT + (size_t)mat * 1048576;

    const bf16_t *ap[4], *bp[4];
#pragma unroll
    for (int i = 0; i < 4; ++i) {
        int cidx = (wave * 4 + i) * 64 + lane;
        int r = cidx >> 3;
        int c = (cidx & 7) ^ (r & 7);
        ap[i] = A    + (size_t)(m0 + r) * DM + c * 8;
        bp[i] = Bmat + (size_t)(n0 + r) * DM + c * 8;
    }

    const v4f vzero = {0.f, 0.f, 0.f, 0.f};
    v4f acc[4][4];
#pragma unroll
    for (int mt = 0; mt < 4; ++mt)
#pragma unroll
        for (int nt = 0; nt < 4; ++nt) acc[mt][nt] = vzero;

    // stage tile 0
#pragma unroll
    for (int i = 0; i < 4; ++i) {
        GLDS16(ap[i], As + (wave * 4 + i) * 512);
        GLDS16(bp[i], Bs + (wave * 4 + i) * 512);
        ap[i] += 64; bp[i] += 64;
    }

    for (int it = 0; it < 16; ++it) {
        __syncthreads();                    // drain staging, tile visible
#pragma unroll
        for (int ks = 0; ks < 2; ++ks) {
            v8bf af[4], bfq[4];
#pragma unroll
            for (int mt = 0; mt < 4; ++mt)
                af[mt] = *reinterpret_cast<const v8bf*>(
                    &As[(wm + mt * 16 + l15) * 64 + ((ks * 4 + quad) ^ l7) * 8]);
#pragma unroll
            for (int nt = 0; nt < 4; ++nt)
                bfq[nt] = *reinterpret_cast<const v8bf*>(
                    &Bs[(wn + nt * 16 + l15) * 64 + ((ks * 4 + quad) ^ l7) * 8]);
#pragma unroll
            for (int mt = 0; mt < 4; ++mt)
#pragma unroll
                for (int nt = 0; nt < 4; ++nt)
                    acc[mt][nt] = MFMA16(bfq[nt], af[mt], acc[mt][nt]);
        }
        __syncthreads();                    // all reads done before restage
        if (it < 15) {
#pragma unroll
            for (int i = 0; i < 4; ++i) {
                GLDS16(ap[i], As + (wave * 4 + i) * 512);
                GLDS16(bp[i], Bs + (wave * 4 + i) * 512);
                ap[i] += 64; bp[i] += 64;
            }
        }
    }

    const float* bias = (mat == 0) ? b0 : (mat == 1) ? b1 : b2;
    if (mat != 2) {
        bf16_t* dst = (mat == 0) ? oQ : oK;
        const float scale = (mat == 0) ? QSCALE : 1.0f;
        const int h = (n0 + wn) >> 6;           // wave-uniform head
#pragma unroll
        for (int nt = 0; nt < 4; ++nt) {
            const int dbase = nt * 16 + quad * 4;           // 4 contiguous d
            float4 bv = *reinterpret_cast<const float4*>(bias + n0 + wn + dbase);
#pragma unroll
            for (int mt = 0; mt < 4; ++mt) {
                int srow = m0 + wm + mt * 16 + l15;
                int b = srow >> 11, s = srow & 2047;
                union { bf16_t hh[4]; int2 v; } u;
                u.hh[0] = (bf16_t)((acc[mt][nt][0] + bv.x) * scale);
                u.hh[1] = (bf16_t)((acc[mt][nt][1] + bv.y) * scale);
                u.hh[2] = (bf16_t)((acc[mt][nt][2] + bv.z) * scale);
                u.hh[3] = (bf16_t)((acc[mt][nt][3] + bv.w) * scale);
                *reinterpret_cast<int2*>(
                    dst + ((size_t)(b * NH + h) * SEQ + s) * HD + dbase) = u.v;
            }
        }
    } else {
        // V [B,H,hd,S]: per (nt,r) fixed d, 16 lanes store contiguous s
#pragma unroll
        for (int nt = 0; nt < 4; ++nt) {
#pragma unroll
            for (int r = 0; r < 4; ++r) {
                int coln = n0 + wn + nt * 16 + quad * 4 + r;   // h*64+d
                float bv = bias[coln];
                int h = coln >> 6, d = coln & 63;
#pragma unroll
                for (int mt = 0; mt < 4; ++mt) {
                    int srow = m0 + wm + mt * 16 + l15;
                    int b = srow >> 11, s = srow & 2047;
                    oV[((size_t)(b * NH + h) * HD + d) * SEQ + s] =
                        (bf16_t)(acc[mt][nt][r] + bv);
                }
            }
        }
    }
}

// ---------------------------------------------------------------------------
// Final projection GEMM.  r16: 64x64 tile, 2-wave (128-thread) blocks,
// single-buffered 16KB LDS, grid (16,64) = 1024 = 4 blocks/CU.
// Wave tile 32x64 (acc 2x4).  m97-style sync structure.
// ---------------------------------------------------------------------------
__global__ __launch_bounds__(128)
void gemm_o_kernel(const bf16_t* __restrict__ A, const bf16_t* __restrict__ BT,
                   const float* __restrict__ bias, float* __restrict__ out)
{
    __shared__ __align__(16) bf16_t As[64 * 64];    // 8 KB
    __shared__ __align__(16) bf16_t Bs[64 * 64];    // 8 KB

    const int tid  = threadIdx.x;
    const int lane = tid & 63;
    const int wave = tid >> 6;              // 0..1
    const int wm   = wave * 32;
    const int quad = lane >> 4;
    const int l15  = lane & 15;
    const int l7   = l15 & 7;

    const int n0 = blockIdx.x * 64;
    const int m0 = blockIdx.y * 64;

    // staging: 4 A + 4 B GLDS per thread (512 16B-chunks each, 128 threads)
    const bf16_t *ap[4], *bp[4];
#pragma unroll
    for (int i = 0; i < 4; ++i) {
        int cidx = wave * 64 + i * 128 + lane;      // 0..511
        int r = cidx >> 3;                          // row 0..63
        int c = (cidx & 7) ^ (r & 7);
        ap[i] = A  + (size_t)(m0 + r) * DM + c * 8;
        bp[i] = BT + (size_t)(n0 + r) * DM + c * 8;
    }

    const v4f vzero = {0.f, 0.f, 0.f, 0.f};
    v4f acc[2][4];
#pragma unroll
    for (int mt = 0; mt < 2; ++mt)
#pragma unroll
        for (int nt = 0; nt < 4; ++nt) acc[mt][nt] = vzero;

    // stage tile 0  (LDS dest base wave-uniform: (wave*64 + i*128)*8 elems)
#pragma unroll
    for (int i = 0; i < 4; ++i) {
        GLDS16(ap[i], As + wave * 512 + i * 1024);
        GLDS16(bp[i], Bs + wave * 512 + i * 1024);
        ap[i] += 64; bp[i] += 64;
    }

    for (int it = 0; it < 16; ++it) {
        __syncthreads();
#pragma unroll
        for (int ks = 0; ks < 2; ++ks) {
            v8bf af[2], bfq[4];
#pragma unroll
            for (int mt = 0; mt < 2; ++mt)
                af[mt] = *reinterpret_cast<const v8bf*>(
                    &As[(wm + mt * 16 + l15) * 64 + ((ks * 4 + quad) ^ l7) * 8]);
#pragma unroll
            for (int nt = 0; nt < 4; ++nt)
                bfq[nt] = *reinterpret_cast<const v8bf*>(
                    &Bs[(nt * 16 + l15) * 64 + ((ks * 4 + quad) ^ l7) * 8]);
#pragma unroll
            for (int mt = 0; mt < 2; ++mt)
#pragma unroll
                for (int nt = 0; nt < 4; ++nt)
                    acc[mt][nt] = MFMA16(af[mt], bfq[nt], acc[mt][nt]);
        }
        __syncthreads();
        if (it < 15) {
#pragma unroll
            for (int i = 0; i < 4; ++i) {
                GLDS16(ap[i], As + wave * 512 + i * 1024);
                GLDS16(bp[i], Bs + wave * 512 + i * 1024);
                ap[i] += 64; bp[i] += 64;
            }
        }
    }

#pragma unroll
    for (int mt = 0; mt < 2; ++mt) {
#pragma unroll
        for (int nt = 0; nt < 4; ++nt) {
            int col = n0 + nt * 16 + l15;
            float bv = bias[col];
#pragma unroll
            for (int r = 0; r < 4; ++r) {
                int row = m0 + wm + mt * 16 + quad * 4 + r;
                out[(size_t)row * DM + col] = acc[mt][nt][r] + bv;
            }
        }
    }
}

// ---------------------------------------------------------------------------
// Flash attention, causal, static-max softmax (unchanged from r15).
// Paired key-tiles on key-split structure; in-register P (k=32 packs both
// tiles); XCD remap; counted-vmcnt 2-pair pipeline; epilogue aliased in LDS.
// Q pre-scaled.  Q,K [B,H,S,hd]; V [B,H,hd,S]; O [B,S,D].
// ---------------------------------------------------------------------------
__global__ __launch_bounds__(256)
void attn_kernel(const bf16_t* __restrict__ Q, const bf16_t* __restrict__ K,
                 const bf16_t* __restrict__ Vt, bf16_t* __restrict__ O)
{
    __shared__ __align__(16) bf16_t Ks[4][64 * 64];
    __shared__ __align__(16) bf16_t Vs[4][64 * 64];
    float* Ored = reinterpret_cast<float*>(&Ks[0][0]);   // 16.6KB alias (post-loop)
    float* lred = reinterpret_cast<float*>(&Vs[0][0]);   // 1KB alias (post-loop)

    const int tid  = threadIdx.x;
    const int lane = tid & 63;
    const int w    = tid >> 6;
    const int quad = lane >> 4;
    const int l15  = lane & 15;
    const int l7   = lane & 7;

    const int bid = blockIdx.x;             // 0..511
    const int xcd = bid & 7;
    const int j   = bid >> 3;               // 0..63
    const int bh  = (xcd << 2) | (j >> 4);  // 4 bh per XCD
    const int p   = j & 15;                 // pair index 0..15
    const size_t base = (size_t)bh * SEQ * HD;
    const bf16_t* Qg = Q  + base;
    const bf16_t* Kg = K  + base;
    const bf16_t* Vg = Vt + base;

    // staging: thread covers rows rr0 and rr0+32, source pre-swizzled col cc0
    const int rr0 = tid >> 3;
    const int cc0 = (tid & 7) ^ (rr0 & 7);
    const int bO = bh >> 4, hO = bh & 15;
    const v4f vzero = {0.f, 0.f, 0.f, 0.f};

    for (int phase = 0; phase < 2; ++phase) {
        const int t  = phase ? (31 - p) : p;   // q-tile index; t0 + t1 = 31
        const int q0 = t * 64;
        const int ns = (t + 2) >> 1;           // super-iters (key-tile pairs)
        const bool tEven = ((t & 1) == 0);

        // ALL 64 q rows in registers: qf[g][ks], g = q-group (16 rows each)
        v8bf qf[4][2];
#pragma unroll
        for (int g = 0; g < 4; ++g) {
            const bf16_t* qrow = Qg + (size_t)(q0 + g * 16 + l15) * HD;
            qf[g][0] = *reinterpret_cast<const v8bf*>(qrow + quad * 8);
            qf[g][1] = *reinterpret_cast<const v8bf*>(qrow + 32 + quad * 8);
        }

        const bf16_t* kp0 = Kg + (size_t)rr0 * HD + cc0 * 8;
        const bf16_t* kp1 = kp0 + 32 * HD;
        const bf16_t* vp0 = Vg + (size_t)rr0 * SEQ + cc0 * 8;
        const bf16_t* vp1 = vp0 + (size_t)32 * SEQ;

        v4f acc_p[4][4];                    // [d-tile][q-group] partial O^T
#pragma unroll
        for (int dt = 0; dt < 4; ++dt)
#pragma unroll
            for (int g = 0; g < 4; ++g) acc_p[dt][g] = vzero;
        float lp[4] = {0.f, 0.f, 0.f, 0.f}; // per-lane l partials per q-group

        // drain qf loads (and prev-phase epilogue stores) -> GLDS-only ledger
        VMEMCNT(0);
        SBAR();              // prev phase's epilogue LDS readers done

        // prologue: pair 0 -> slots 0,1; pair 1 -> slots 2,3 (8 GLDS each)
#pragma unroll
        for (int s = 0; s < 2; ++s) {
            GLDS16(kp0, &Ks[s][w * 512]);  GLDS16(kp1, &Ks[s][2048 + w * 512]);
            GLDS16(vp0, &Vs[s][w * 512]);  GLDS16(vp1, &Vs[s][2048 + w * 512]);
            kp0 += 64 * HD;  kp1 += 64 * HD;  vp0 += 64;  vp1 += 64;
        }
        if (ns > 1) {
#pragma unroll
            for (int s = 2; s < 4; ++s) {
                GLDS16(kp0, &Ks[s][w * 512]);  GLDS16(kp1, &Ks[s][2048 + w * 512]);
                GLDS16(vp0, &Vs[s][w * 512]);  GLDS16(vp1, &Vs[s][2048 + w * 512]);
                kp0 += 64 * HD;  kp1 += 64 * HD;  vp0 += 64;  vp1 += 64;
            }
        }

        for (int si = 0; si < ns; ++si) {
            const int sA = (si & 1) * 2, sB = sA + 1;
            if (si + 1 < ns) { VMEMCNT(8); } else { VMEMCNT(0); }  // pair si done
            SBAR(); SFENCE();

            const bool last  = (si == ns - 1);
            const bool diagA = last && tEven;     // also: tile B fully masked
            const bool diagB = last && !tEven;

            // S^T on this wave's 16-key slice, tiles A and B
            v4f stA[4], stB[4];
#pragma unroll
            for (int g = 0; g < 4; ++g) { stA[g] = vzero; stB[g] = vzero; }
#pragma unroll
            for (int ks = 0; ks < 2; ++ks) {
                const int koff = (16 * w + l15) * 64 + ((ks * 4 + quad) ^ l7) * 8;
                v8bf kfA = *reinterpret_cast<const v8bf*>(&Ks[sA][koff]);
                v8bf kfB = *reinterpret_cast<const v8bf*>(&Ks[sB][koff]);
#pragma unroll
                for (int g = 0; g < 4; ++g) {
                    stA[g] = MFMA16(kfA, qf[g][ks], stA[g]);
                    stB[g] = MFMA16(kfB, qf[g][ks], stB[g]);
                }
            }
            // stX[g][r] = S[key = 16w + quad*4 + r (of tile X)][q = g*16 + l15]

            // softmax (static-max): pack BOTH tiles into one k=32 B-frag:
            // k = quad*8+j: j<4 -> tile A key 16w+quad*4+j; j>=4 -> tile B
            v8bf pa[4];
#pragma unroll
            for (int g = 0; g < 4; ++g) {
                union { bf16_t h[8]; v8bf v; } up;
                // tile A half (j = 0..3)
                if (diagA && g < w) {
                    up.h[0] = (bf16_t)0.f; up.h[1] = (bf16_t)0.f;
                    up.h[2] = (bf16_t)0.f; up.h[3] = (bf16_t)0.f;
                } else if (diagA && g == w) {
#pragma unroll
                    for (int r = 0; r < 4; ++r) {
                        float pv = (quad * 4 + r > l15)
                                     ? 0.f : __builtin_amdgcn_exp2f(stA[g][r]);
                        lp[g] += pv;
                        up.h[r] = (bf16_t)pv;
                    }
                } else {
#pragma unroll
                    for (int r = 0; r < 4; ++r) {
                        float pv = __builtin_amdgcn_exp2f(stA[g][r]);
                        lp[g] += pv;
                        up.h[r] = (bf16_t)pv;
                    }
                }
                // tile B half (j = 4..7); diagA implies B fully masked
                if (diagA || (diagB && g < w)) {
                    up.h[4] = (bf16_t)0.f; up.h[5] = (bf16_t)0.f;
                    up.h[6] = (bf16_t)0.f; up.h[7] = (bf16_t)0.f;
                } else if (diagB && g == w) {
#pragma unroll
                    for (int r = 0; r < 4; ++r) {
                        float pv = (quad * 4 + r > l15)
                                     ? 0.f : __builtin_amdgcn_exp2f(stB[g][r]);
                        lp[g] += pv;
                        up.h[4 + r] = (bf16_t)pv;
                    }
                } else {
#pragma unroll
                    for (int r = 0; r < 4; ++r) {
                        float pv = __builtin_amdgcn_exp2f(stB[g][r]);
                        lp[g] += pv;
                        up.h[4 + r] = (bf16_t)pv;
                    }
                }
                pa[g] = up.v;
            }

            // O^T_partial += V^T P  (full k=32: tile A keys j<4, tile B j>=4)
#pragma unroll
            for (int dt = 0; dt < 4; ++dt) {
                const int rowd = dt * 16 + l15;
                const int voff = rowd * 64 +
                    (((2 * w + (quad >> 1)) ^ l7) * 8 + (quad & 1) * 4);
                uint2 va = *reinterpret_cast<const uint2*>(&Vs[sA][voff]);
                uint2 vb = *reinterpret_cast<const uint2*>(&Vs[sB][voff]);
                union { unsigned u[4]; v8bf v; } uv;
                uv.u[0] = va.x; uv.u[1] = va.y; uv.u[2] = vb.x; uv.u[3] = vb.y;
#pragma unroll
                for (int g = 0; g < 4; ++g)
                    acc_p[dt][g] = MFMA16(uv.v, pa[g], acc_p[dt][g]);
            }

            SFENCE(); SBAR();               // all waves done with pair si
            if (si + 2 < ns) {              // stage pair si+2 into slots sA,sB
                GLDS16(kp0, &Ks[sA][w * 512]);  GLDS16(kp1, &Ks[sA][2048 + w * 512]);
                GLDS16(vp0, &Vs[sA][w * 512]);  GLDS16(vp1, &Vs[sA][2048 + w * 512]);
                kp0 += 64 * HD;  kp1 += 64 * HD;  vp0 += 64;  vp1 += 64;
                GLDS16(kp0, &Ks[sB][w * 512]);  GLDS16(kp1, &Ks[sB][2048 + w * 512]);
                GLDS16(vp0, &Vs[sB][w * 512]);  GLDS16(vp1, &Vs[sB][2048 + w * 512]);
                kp0 += 64 * HD;  kp1 += 64 * HD;  vp0 += 64;  vp1 += 64;
            }
        }

        // ---- phase epilogue: cross-wave reduction of O partials and l ----
        // (Ored/lred alias Ks/Vs: all K/V reads completed at last bottom SBAR)
#pragma unroll
        for (int g = 0; g < 4; ++g) {
            lp[g] += __shfl_xor(lp[g], 16);
            lp[g] += __shfl_xor(lp[g], 32);
        }
        if (quad == 0) {
#pragma unroll
            for (int g = 0; g < 4; ++g)
                lred[w * 64 + g * 16 + l15] = lp[g];
        }

        const int qq = tid >> 2;            // q within tile, 0..63
        const int db = (tid & 3) * 4;       // d-quad within 16-d tile
        float linv = 0.f;
#pragma unroll
        for (int dt = 0; dt < 4; ++dt) {
            // each wave writes its partial for this 16-d tile (stride-65 pad)
#pragma unroll
            for (int g = 0; g < 4; ++g)
#pragma unroll
                for (int r = 0; r < 4; ++r)
                    Ored[w * 1040 + (quad * 4 + r) * 65 + g * 16 + l15] =
                        acc_p[dt][g][r];
            SBAR();
            if (dt == 0)
                linv = 1.f / (lred[qq] + lred[64 + qq] +
                              lred[128 + qq] + lred[192 + qq]);
            union { bf16_t h[4]; int2 v; } u;
#pragma unroll
            for (int e = 0; e < 4; ++e) {
                float s = Ored[(db + e) * 65 + qq]
                        + Ored[1040 + (db + e) * 65 + qq]
                        + Ored[2080 + (db + e) * 65 + qq]
                        + Ored[3120 + (db + e) * 65 + qq];
                u.h[e] = (bf16_t)(s * linv);
            }
            *reinterpret_cast<int2*>(
                &O[((size_t)bO * SEQ + q0 + qq) * DM + hO * 64 + dt * 16 + db]) = u.v;
            SBAR();                         // reads done before next round
        }
    }
}

// ---------------------------------------------------------------------------
extern "C" void kernel_launch(void* const* d_in, const int* in_sizes, int n_in,
                              void* d_out, int out_size, void* d_ws, size_t ws_size,
                              hipStream_t stream) {
    const float* x  = (const float*)d_in[0];
    const float* Wq = (const float*)d_in[1];
    const float* bq = (const float*)d_in[2];
    const float* Wk = (const float*)d_in[3];
    const float* bk = (const float*)d_in[4];
    const float* Wv = (const float*)d_in[5];
    const float* bv = (const float*)d_in[6];
    const float* Wo = (const float*)d_in[7];
    const float* bo = (const float*)d_in[8];

    bf16_t* ws = (bf16_t*)d_ws;
    bf16_t* xb     = ws;                   // [4096,1024]        4M  (dead after QKV)
    bf16_t* WqkvT  = ws + 4194304;         // [3,1024n,1024k]    3M (flat [3072][1024])
    bf16_t* WoT    = ws + 7340032;         // [1024n,1024k]      1M
    bf16_t* Qb     = ws + 8388608;         // [B,H,S,hd]  pre-scaled 0.125*log2(e)
    bf16_t* Kb     = ws + 12582912;        // [B,H,S,hd]
    bf16_t* Vb     = ws + 16777216;        // [B,H,hd,S]
    bf16_t* Ob     = ws;                   // [B,S,D]  aliases xb (stream-ordered safe)

    conv_x_kernel<<<2048, 256, 0, stream>>>(x, xb);
    conv_wt_kernel<<<dim3(32, 32, 4), 256, 0, stream>>>(Wq, Wk, Wv, Wo, WqkvT, WoT);
    gemm_qkv_kernel<<<dim3(24, 32), 256, 0, stream>>>(xb, WqkvT, bq, bk, bv, Qb, Kb, Vb);
    attn_kernel<<<512, 256, 0, stream>>>(Qb, Kb, Vb, Ob);
    gemm_o_kernel<<<dim3(16, 64), 128, 0, stream>>>(Ob, WoT, bo, (float*)d_out);
}

// Round 8
// 175.517 us; speedup vs baseline: 1.0273x; 1.0273x over previous
//
#include <hip/hip_runtime.h>
#include <hip/hip_bf16.h>

typedef __bf16 bf16_t;
typedef __bf16 v8bf __attribute__((ext_vector_type(8)));
typedef float  v4f  __attribute__((ext_vector_type(4)));

#define MFMA16(a, b, c) __builtin_amdgcn_mfma_f32_16x16x32_bf16((a), (b), (c), 0, 0, 0)

#define GLDS16(g, l) __builtin_amdgcn_global_load_lds(                         \
    (const __attribute__((address_space(1))) void*)(g),                        \
    (__attribute__((address_space(3))) void*)(l), 16, 0, 0)

// counted-vmcnt sync primitives: raw barrier, no implicit vmcnt(0) drain
#define VMEMCNT(n) asm volatile("s_waitcnt vmcnt(" #n ")" ::: "memory")
#define SBAR()     __builtin_amdgcn_s_barrier()
#define SFENCE()   __builtin_amdgcn_sched_barrier(0)

#define B_SZ   2
#define SEQ    2048
#define DM     1024
#define NH     16
#define HD     64
#define M_TOT  4096

// 0.125 * log2(e): Q pre-scale so softmax uses exp2 with no multiply
#define QSCALE 0.18033688011112043f

// ---------------------------------------------------------------------------
// convert x fp32 -> bf16  (4M elems, 8/thread)
// ---------------------------------------------------------------------------
__global__ __launch_bounds__(256)
void conv_x_kernel(const float* __restrict__ src, bf16_t* __restrict__ dst)
{
    int i = (blockIdx.x * 256 + threadIdx.x) * 8;
    float4 a = *reinterpret_cast<const float4*>(src + i);
    float4 b = *reinterpret_cast<const float4*>(src + i + 4);
    union { bf16_t h[8]; int4 v; } u;
    u.h[0] = (bf16_t)a.x; u.h[1] = (bf16_t)a.y; u.h[2] = (bf16_t)a.z; u.h[3] = (bf16_t)a.w;
    u.h[4] = (bf16_t)b.x; u.h[5] = (bf16_t)b.y; u.h[6] = (bf16_t)b.z; u.h[7] = (bf16_t)b.w;
    *reinterpret_cast<int4*>(dst + i) = u.v;
}

// ---------------------------------------------------------------------------
// transpose+convert W fp32 [k][n] -> bf16 [n][k].  grid (32,32,4)
// ---------------------------------------------------------------------------
__global__ __launch_bounds__(256)
void conv_wt_kernel(const float* __restrict__ Wq, const float* __restrict__ Wk,
                    const float* __restrict__ Wv, const float* __restrict__ Wo,
                    bf16_t* __restrict__ WqkvT, bf16_t* __restrict__ WoT)
{
    __shared__ float t[32][33];
    const int z = blockIdx.z;
    const float* src = (z == 0) ? Wq : (z == 1) ? Wk : (z == 2) ? Wv : Wo;
    bf16_t* dst = (z < 3) ? (WqkvT + (size_t)z * 1048576) : WoT;
    const int tx = threadIdx.x & 31, ty = threadIdx.x >> 5;
    const int c0 = blockIdx.x * 32, r0 = blockIdx.y * 32;
#pragma unroll
    for (int i = 0; i < 4; ++i)
        t[ty + i * 8][tx] = src[(size_t)(r0 + ty + i * 8) * DM + c0 + tx];
    __syncthreads();
#pragma unroll
    for (int i = 0; i < 4; ++i)
        dst[(size_t)(c0 + ty + i * 8) * DM + r0 + tx] = (bf16_t)t[tx][ty + i * 8];
}

// ---------------------------------------------------------------------------
// Fused QKV GEMM.  r17 = exact r12 config (proven fastest: ~39-40us).
// 128x192 tile, dbuf, counted-vmcnt pipeline, grid (16,32) = 2 blocks/CU.
// (r16's single-buffered 128x128 @3/CU regressed to 51.7us - reverted.)
// ---------------------------------------------------------------------------
__global__ __launch_bounds__(256)
void gemm_qkv_kernel(const bf16_t* __restrict__ A, const bf16_t* __restrict__ BT,
                     const float* __restrict__ b0, const float* __restrict__ b1,
                     const float* __restrict__ b2,
                     bf16_t* __restrict__ oQ, bf16_t* __restrict__ oK,
                     bf16_t* __restrict__ oV)
{
    __shared__ __align__(16) bf16_t As[2 * 128 * 64];   // 32 KB
    __shared__ __align__(16) bf16_t Bs[2 * 192 * 64];   // 48 KB

    const int tid  = threadIdx.x;
    const int lane = tid & 63;
    const int wave = tid >> 6;
    const int wm   = (wave >> 1) * 64;
    const int wn   = (wave & 1) * 96;
    const int quad = lane >> 4;
    const int l15  = lane & 15;
    const int l7   = l15 & 7;

    const int n0 = blockIdx.x * 192;        // flat col in [0,3072)
    const int m0 = blockIdx.y * 128;

    // staging pointers: A 4 loads/thread, B 6 loads/thread (16B each)
    const bf16_t *ap[4], *bp[6];
#pragma unroll
    for (int i = 0; i < 4; ++i) {
        int cidx = (wave * 4 + i) * 64 + lane;          // [0,1024): 128 rows x 8
        int r = cidx >> 3;
        int c = (cidx & 7) ^ (r & 7);
        ap[i] = A + (size_t)(m0 + r) * DM + c * 8;
    }
#pragma unroll
    for (int i = 0; i < 6; ++i) {
        int cidx = (wave * 6 + i) * 64 + lane;          // [0,1536): 192 rows x 8
        int r = cidx >> 3;
        int c = (cidx & 7) ^ (r & 7);
        bp[i] = BT + (size_t)(n0 + r) * DM + c * 8;     // BT flat [3072][1024]
    }

    const v4f vzero = {0.f, 0.f, 0.f, 0.f};
    v4f acc[4][6];
#pragma unroll
    for (int mt = 0; mt < 4; ++mt)
#pragma unroll
        for (int nt = 0; nt < 6; ++nt) acc[mt][nt] = vzero;

    // prologue: tile 0 -> buf 0, tile 1 -> buf 1  (20 loads in flight)
#pragma unroll
    for (int i = 0; i < 4; ++i) { GLDS16(ap[i], As + (wave * 4 + i) * 512); ap[i] += 64; }
#pragma unroll
    for (int i = 0; i < 6; ++i) { GLDS16(bp[i], Bs + (wave * 6 + i) * 512); bp[i] += 64; }
#pragma unroll
    for (int i = 0; i < 4; ++i) { GLDS16(ap[i], As + 8192 + (wave * 4 + i) * 512); ap[i] += 64; }
#pragma unroll
    for (int i = 0; i < 6; ++i) { GLDS16(bp[i], Bs + 12288 + (wave * 6 + i) * 512); bp[i] += 64; }

    for (int it = 0; it < 16; ++it) {
        const int cur = it & 1;
        if (it < 15) { VMEMCNT(10); } else { VMEMCNT(0); }  // tile it complete
        SBAR(); SFENCE();
#pragma unroll
        for (int ks = 0; ks < 2; ++ks) {
            v8bf af[4], bfq[6];
#pragma unroll
            for (int mt = 0; mt < 4; ++mt)
                af[mt] = *reinterpret_cast<const v8bf*>(
                    &As[cur * 8192 + (wm + mt * 16 + l15) * 64 + ((ks * 4 + quad) ^ l7) * 8]);
#pragma unroll
            for (int nt = 0; nt < 6; ++nt)
                bfq[nt] = *reinterpret_cast<const v8bf*>(
                    &Bs[cur * 12288 + (wn + nt * 16 + l15) * 64 + ((ks * 4 + quad) ^ l7) * 8]);
#pragma unroll
            for (int mt = 0; mt < 4; ++mt)
#pragma unroll
                for (int nt = 0; nt < 6; ++nt)
                    acc[mt][nt] = MFMA16(bfq[nt], af[mt], acc[mt][nt]);
        }
        SFENCE(); SBAR();                   // all waves done reading buf cur
        if (it < 14) {                      // stage tile it+2 into buf cur
#pragma unroll
            for (int i = 0; i < 4; ++i) {
                GLDS16(ap[i], As + cur * 8192 + (wave * 4 + i) * 512);
                ap[i] += 64;
            }
#pragma unroll
            for (int i = 0; i < 6; ++i) {
                GLDS16(bp[i], Bs + cur * 12288 + (wave * 6 + i) * 512);
                bp[i] += 64;
            }
        }
    }

    // epilogue: per 16-wide n-frag resolve matrix / head / bias
#pragma unroll
    for (int nt = 0; nt < 6; ++nt) {
        const int cf0 = n0 + wn + nt * 16;      // flat col base of frag
        const int mat = cf0 >> 10;              // 0=Q 1=K 2=V (frag-uniform)
        const int cw  = cf0 & 1023;             // within-matrix col base
        if (mat != 2) {
            bf16_t* dst = (mat == 0) ? oQ : oK;
            const float scale = (mat == 0) ? QSCALE : 1.0f;
            const float* bias = (mat == 0) ? b0 : b1;
            const int h = cw >> 6;
            const int dbase = (cw & 63) + quad * 4;     // 4 contiguous d
            float4 bv = *reinterpret_cast<const float4*>(bias + cw + quad * 4);
#pragma unroll
            for (int mt = 0; mt < 4; ++mt) {
                int srow = m0 + wm + mt * 16 + l15;
                int b = srow >> 11, s = srow & 2047;
                union { bf16_t hh[4]; int2 v; } u;
                u.hh[0] = (bf16_t)((acc[mt][nt][0] + bv.x) * scale);
                u.hh[1] = (bf16_t)((acc[mt][nt][1] + bv.y) * scale);
                u.hh[2] = (bf16_t)((acc[mt][nt][2] + bv.z) * scale);
                u.hh[3] = (bf16_t)((acc[mt][nt][3] + bv.w) * scale);
                *reinterpret_cast<int2*>(
                    dst + ((size_t)(b * NH + h) * SEQ + s) * HD + dbase) = u.v;
            }
        } else {
            // V [B,H,hd,S]: per r fixed d, 16 lanes store contiguous s
#pragma unroll
            for (int r = 0; r < 4; ++r) {
                int cwe = cw + quad * 4 + r;            // h*64+d
                float bvv = b2[cwe];
                int h = cwe >> 6, d = cwe & 63;
#pragma unroll
                for (int mt = 0; mt < 4; ++mt) {
                    int srow = m0 + wm + mt * 16 + l15;
                    int b = srow >> 11, s = srow & 2047;
                    oV[((size_t)(b * NH + h) * HD + d) * SEQ + s] =
                        (bf16_t)(acc[mt][nt][r] + bvv);
                }
            }
        }
    }
}

// ---------------------------------------------------------------------------
// Final projection GEMM.  r16 version (kept - it improved ~5.6us):
// 64x64 tile, 2-wave (128-thread) blocks, single-buffered 16KB LDS,
// grid (16,64) = 1024 = 4 blocks/CU.  Wave tile 32x64 (acc 2x4).
// ---------------------------------------------------------------------------
__global__ __launch_bounds__(128)
void gemm_o_kernel(const bf16_t* __restrict__ A, const bf16_t* __restrict__ BT,
                   const float* __restrict__ bias, float* __restrict__ out)
{
    __shared__ __align__(16) bf16_t As[64 * 64];    // 8 KB
    __shared__ __align__(16) bf16_t Bs[64 * 64];    // 8 KB

    const int tid  = threadIdx.x;
    const int lane = tid & 63;
    const int wave = tid >> 6;              // 0..1
    const int wm   = wave * 32;
    const int quad = lane >> 4;
    const int l15  = lane & 15;
    const int l7   = l15 & 7;

    const int n0 = blockIdx.x * 64;
    const int m0 = blockIdx.y * 64;

    // staging: 4 A + 4 B GLDS per thread (512 16B-chunks each, 128 threads)
    const bf16_t *ap[4], *bp[4];
#pragma unroll
    for (int i = 0; i < 4; ++i) {
        int cidx = wave * 64 + i * 128 + lane;      // 0..511
        int r = cidx >> 3;                          // row 0..63
        int c = (cidx & 7) ^ (r & 7);
        ap[i] = A  + (size_t)(m0 + r) * DM + c * 8;
        bp[i] = BT + (size_t)(n0 + r) * DM + c * 8;
    }

    const v4f vzero = {0.f, 0.f, 0.f, 0.f};
    v4f acc[2][4];
#pragma unroll
    for (int mt = 0; mt < 2; ++mt)
#pragma unroll
        for (int nt = 0; nt < 4; ++nt) acc[mt][nt] = vzero;

    // stage tile 0  (LDS dest base wave-uniform: (wave*64 + i*128)*8 elems)
#pragma unroll
    for (int i = 0; i < 4; ++i) {
        GLDS16(ap[i], As + wave * 512 + i * 1024);
        GLDS16(bp[i], Bs + wave * 512 + i * 1024);
        ap[i] += 64; bp[i] += 64;
    }

    for (int it = 0; it < 16; ++it) {
        __syncthreads();
#pragma unroll
        for (int ks = 0; ks < 2; ++ks) {
            v8bf af[2], bfq[4];
#pragma unroll
            for (int mt = 0; mt < 2; ++mt)
                af[mt] = *reinterpret_cast<const v8bf*>(
                    &As[(wm + mt * 16 + l15) * 64 + ((ks * 4 + quad) ^ l7) * 8]);
#pragma unroll
            for (int nt = 0; nt < 4; ++nt)
                bfq[nt] = *reinterpret_cast<const v8bf*>(
                    &Bs[(nt * 16 + l15) * 64 + ((ks * 4 + quad) ^ l7) * 8]);
#pragma unroll
            for (int mt = 0; mt < 2; ++mt)
#pragma unroll
                for (int nt = 0; nt < 4; ++nt)
                    acc[mt][nt] = MFMA16(af[mt], bfq[nt], acc[mt][nt]);
        }
        __syncthreads();
        if (it < 15) {
#pragma unroll
            for (int i = 0; i < 4; ++i) {
                GLDS16(ap[i], As + wave * 512 + i * 1024);
                GLDS16(bp[i], Bs + wave * 512 + i * 1024);
                ap[i] += 64; bp[i] += 64;
            }
        }
    }

#pragma unroll
    for (int mt = 0; mt < 2; ++mt) {
#pragma unroll
        for (int nt = 0; nt < 4; ++nt) {
            int col = n0 + nt * 16 + l15;
            float bv = bias[col];
#pragma unroll
            for (int r = 0; r < 4; ++r) {
                int row = m0 + wm + mt * 16 + quad * 4 + r;
                out[(size_t)row * DM + col] = acc[mt][nt][r] + bv;
            }
        }
    }
}

// ---------------------------------------------------------------------------
// Flash attention, causal, static-max softmax (unchanged from r15).
// Paired key-tiles on key-split structure; in-register P (k=32 packs both
// tiles); XCD remap; counted-vmcnt 2-pair pipeline; epilogue aliased in LDS.
// Q pre-scaled.  Q,K [B,H,S,hd]; V [B,H,hd,S]; O [B,S,D].
// ---------------------------------------------------------------------------
__global__ __launch_bounds__(256)
void attn_kernel(const bf16_t* __restrict__ Q, const bf16_t* __restrict__ K,
                 const bf16_t* __restrict__ Vt, bf16_t* __restrict__ O)
{
    __shared__ __align__(16) bf16_t Ks[4][64 * 64];
    __shared__ __align__(16) bf16_t Vs[4][64 * 64];
    float* Ored = reinterpret_cast<float*>(&Ks[0][0]);   // 16.6KB alias (post-loop)
    float* lred = reinterpret_cast<float*>(&Vs[0][0]);   // 1KB alias (post-loop)

    const int tid  = threadIdx.x;
    const int lane = tid & 63;
    const int w    = tid >> 6;
    const int quad = lane >> 4;
    const int l15  = lane & 15;
    const int l7   = lane & 7;

    const int bid = blockIdx.x;             // 0..511
    const int xcd = bid & 7;
    const int j   = bid >> 3;               // 0..63
    const int bh  = (xcd << 2) | (j >> 4);  // 4 bh per XCD
    const int p   = j & 15;                 // pair index 0..15
    const size_t base = (size_t)bh * SEQ * HD;
    const bf16_t* Qg = Q  + base;
    const bf16_t* Kg = K  + base;
    const bf16_t* Vg = Vt + base;

    // staging: thread covers rows rr0 and rr0+32, source pre-swizzled col cc0
    const int rr0 = tid >> 3;
    const int cc0 = (tid & 7) ^ (rr0 & 7);
    const int bO = bh >> 4, hO = bh & 15;
    const v4f vzero = {0.f, 0.f, 0.f, 0.f};

    for (int phase = 0; phase < 2; ++phase) {
        const int t  = phase ? (31 - p) : p;   // q-tile index; t0 + t1 = 31
        const int q0 = t * 64;
        const int ns = (t + 2) >> 1;           // super-iters (key-tile pairs)
        const bool tEven = ((t & 1) == 0);

        // ALL 64 q rows in registers: qf[g][ks], g = q-group (16 rows each)
        v8bf qf[4][2];
#pragma unroll
        for (int g = 0; g < 4; ++g) {
            const bf16_t* qrow = Qg + (size_t)(q0 + g * 16 + l15) * HD;
            qf[g][0] = *reinterpret_cast<const v8bf*>(qrow + quad * 8);
            qf[g][1] = *reinterpret_cast<const v8bf*>(qrow + 32 + quad * 8);
        }

        const bf16_t* kp0 = Kg + (size_t)rr0 * HD + cc0 * 8;
        const bf16_t* kp1 = kp0 + 32 * HD;
        const bf16_t* vp0 = Vg + (size_t)rr0 * SEQ + cc0 * 8;
        const bf16_t* vp1 = vp0 + (size_t)32 * SEQ;

        v4f acc_p[4][4];                    // [d-tile][q-group] partial O^T
#pragma unroll
        for (int dt = 0; dt < 4; ++dt)
#pragma unroll
            for (int g = 0; g < 4; ++g) acc_p[dt][g] = vzero;
        float lp[4] = {0.f, 0.f, 0.f, 0.f}; // per-lane l partials per q-group

        // drain qf loads (and prev-phase epilogue stores) -> GLDS-only ledger
        VMEMCNT(0);
        SBAR();              // prev phase's epilogue LDS readers done

        // prologue: pair 0 -> slots 0,1; pair 1 -> slots 2,3 (8 GLDS each)
#pragma unroll
        for (int s = 0; s < 2; ++s) {
            GLDS16(kp0, &Ks[s][w * 512]);  GLDS16(kp1, &Ks[s][2048 + w * 512]);
            GLDS16(vp0, &Vs[s][w * 512]);  GLDS16(vp1, &Vs[s][2048 + w * 512]);
            kp0 += 64 * HD;  kp1 += 64 * HD;  vp0 += 64;  vp1 += 64;
        }
        if (ns > 1) {
#pragma unroll
            for (int s = 2; s < 4; ++s) {
                GLDS16(kp0, &Ks[s][w * 512]);  GLDS16(kp1, &Ks[s][2048 + w * 512]);
                GLDS16(vp0, &Vs[s][w * 512]);  GLDS16(vp1, &Vs[s][2048 + w * 512]);
                kp0 += 64 * HD;  kp1 += 64 * HD;  vp0 += 64;  vp1 += 64;
            }
        }

        for (int si = 0; si < ns; ++si) {
            const int sA = (si & 1) * 2, sB = sA + 1;
            if (si + 1 < ns) { VMEMCNT(8); } else { VMEMCNT(0); }  // pair si done
            SBAR(); SFENCE();

            const bool last  = (si == ns - 1);
            const bool diagA = last && tEven;     // also: tile B fully masked
            const bool diagB = last && !tEven;

            // S^T on this wave's 16-key slice, tiles A and B
            v4f stA[4], stB[4];
#pragma unroll
            for (int g = 0; g < 4; ++g) { stA[g] = vzero; stB[g] = vzero; }
#pragma unroll
            for (int ks = 0; ks < 2; ++ks) {
                const int koff = (16 * w + l15) * 64 + ((ks * 4 + quad) ^ l7) * 8;
                v8bf kfA = *reinterpret_cast<const v8bf*>(&Ks[sA][koff]);
                v8bf kfB = *reinterpret_cast<const v8bf*>(&Ks[sB][koff]);
#pragma unroll
                for (int g = 0; g < 4; ++g) {
                    stA[g] = MFMA16(kfA, qf[g][ks], stA[g]);
                    stB[g] = MFMA16(kfB, qf[g][ks], stB[g]);
                }
            }
            // stX[g][r] = S[key = 16w + quad*4 + r (of tile X)][q = g*16 + l15]

            // softmax (static-max): pack BOTH tiles into one k=32 B-frag:
            // k = quad*8+j: j<4 -> tile A key 16w+quad*4+j; j>=4 -> tile B
            v8bf pa[4];
#pragma unroll
            for (int g = 0; g < 4; ++g) {
                union { bf16_t h[8]; v8bf v; } up;
                // tile A half (j = 0..3)
                if (diagA && g < w) {
                    up.h[0] = (bf16_t)0.f; up.h[1] = (bf16_t)0.f;
                    up.h[2] = (bf16_t)0.f; up.h[3] = (bf16_t)0.f;
                } else if (diagA && g == w) {
#pragma unroll
                    for (int r = 0; r < 4; ++r) {
                        float pv = (quad * 4 + r > l15)
                                     ? 0.f : __builtin_amdgcn_exp2f(stA[g][r]);
                        lp[g] += pv;
                        up.h[r] = (bf16_t)pv;
                    }
                } else {
#pragma unroll
                    for (int r = 0; r < 4; ++r) {
                        float pv = __builtin_amdgcn_exp2f(stA[g][r]);
                        lp[g] += pv;
                        up.h[r] = (bf16_t)pv;
                    }
                }
                // tile B half (j = 4..7); diagA implies B fully masked
                if (diagA || (diagB && g < w)) {
                    up.h[4] = (bf16_t)0.f; up.h[5] = (bf16_t)0.f;
                    up.h[6] = (bf16_t)0.f; up.h[7] = (bf16_t)0.f;
                } else if (diagB && g == w) {
#pragma unroll
                    for (int r = 0; r < 4; ++r) {
                        float pv = (quad * 4 + r > l15)
                                     ? 0.f : __builtin_amdgcn_exp2f(stB[g][r]);
                        lp[g] += pv;
                        up.h[4 + r] = (bf16_t)pv;
                    }
                } else {
#pragma unroll
                    for (int r = 0; r < 4; ++r) {
                        float pv = __builtin_amdgcn_exp2f(stB[g][r]);
                        lp[g] += pv;
                        up.h[4 + r] = (bf16_t)pv;
                    }
                }
                pa[g] = up.v;
            }

            // O^T_partial += V^T P  (full k=32: tile A keys j<4, tile B j>=4)
#pragma unroll
            for (int dt = 0; dt < 4; ++dt) {
                const int rowd = dt * 16 + l15;
                const int voff = rowd * 64 +
                    (((2 * w + (quad >> 1)) ^ l7) * 8 + (quad & 1) * 4);
                uint2 va = *reinterpret_cast<const uint2*>(&Vs[sA][voff]);
                uint2 vb = *reinterpret_cast<const uint2*>(&Vs[sB][voff]);
                union { unsigned u[4]; v8bf v; } uv;
                uv.u[0] = va.x; uv.u[1] = va.y; uv.u[2] = vb.x; uv.u[3] = vb.y;
#pragma unroll
                for (int g = 0; g < 4; ++g)
                    acc_p[dt][g] = MFMA16(uv.v, pa[g], acc_p[dt][g]);
            }

            SFENCE(); SBAR();               // all waves done with pair si
            if (si + 2 < ns) {              // stage pair si+2 into slots sA,sB
                GLDS16(kp0, &Ks[sA][w * 512]);  GLDS16(kp1, &Ks[sA][2048 + w * 512]);
                GLDS16(vp0, &Vs[sA][w * 512]);  GLDS16(vp1, &Vs[sA][2048 + w * 512]);
                kp0 += 64 * HD;  kp1 += 64 * HD;  vp0 += 64;  vp1 += 64;
                GLDS16(kp0, &Ks[sB][w * 512]);  GLDS16(kp1, &Ks[sB][2048 + w * 512]);
                GLDS16(vp0, &Vs[sB][w * 512]);  GLDS16(vp1, &Vs[sB][2048 + w * 512]);
                kp0 += 64 * HD;  kp1 += 64 * HD;  vp0 += 64;  vp1 += 64;
            }
        }

        // ---- phase epilogue: cross-wave reduction of O partials and l ----
        // (Ored/lred alias Ks/Vs: all K/V reads completed at last bottom SBAR)
#pragma unroll
        for (int g = 0; g < 4; ++g) {
            lp[g] += __shfl_xor(lp[g], 16);
            lp[g] += __shfl_xor(lp[g], 32);
        }
        if (quad == 0) {
#pragma unroll
            for (int g = 0; g < 4; ++g)
                lred[w * 64 + g * 16 + l15] = lp[g];
        }

        const int qq = tid >> 2;            // q within tile, 0..63
        const int db = (tid & 3) * 4;       // d-quad within 16-d tile
        float linv = 0.f;
#pragma unroll
        for (int dt = 0; dt < 4; ++dt) {
            // each wave writes its partial for this 16-d tile (stride-65 pad)
#pragma unroll
            for (int g = 0; g < 4; ++g)
#pragma unroll
                for (int r = 0; r < 4; ++r)
                    Ored[w * 1040 + (quad * 4 + r) * 65 + g * 16 + l15] =
                        acc_p[dt][g][r];
            SBAR();
            if (dt == 0)
                linv = 1.f / (lred[qq] + lred[64 + qq] +
                              lred[128 + qq] + lred[192 + qq]);
            union { bf16_t h[4]; int2 v; } u;
#pragma unroll
            for (int e = 0; e < 4; ++e) {
                float s = Ored[(db + e) * 65 + qq]
                        + Ored[1040 + (db + e) * 65 + qq]
                        + Ored[2080 + (db + e) * 65 + qq]
                        + Ored[3120 + (db + e) * 65 + qq];
                u.h[e] = (bf16_t)(s * linv);
            }
            *reinterpret_cast<int2*>(
                &O[((size_t)bO * SEQ + q0 + qq) * DM + hO * 64 + dt * 16 + db]) = u.v;
            SBAR();                         // reads done before next round
        }
    }
}

// ---------------------------------------------------------------------------
extern "C" void kernel_launch(void* const* d_in, const int* in_sizes, int n_in,
                              void* d_out, int out_size, void* d_ws, size_t ws_size,
                              hipStream_t stream) {
    const float* x  = (const float*)d_in[0];
    const float* Wq = (const float*)d_in[1];
    const float* bq = (const float*)d_in[2];
    const float* Wk = (const float*)d_in[3];
    const float* bk = (const float*)d_in[4];
    const float* Wv = (const float*)d_in[5];
    const float* bv = (const float*)d_in[6];
    const float* Wo = (const float*)d_in[7];
    const float* bo = (const float*)d_in[8];

    bf16_t* ws = (bf16_t*)d_ws;
    bf16_t* xb     = ws;                   // [4096,1024]        4M  (dead after QKV)
    bf16_t* WqkvT  = ws + 4194304;         // [3,1024n,1024k]    3M (flat [3072][1024])
    bf16_t* WoT    = ws + 7340032;         // [1024n,1024k]      1M
    bf16_t* Qb     = ws + 8388608;         // [B,H,S,hd]  pre-scaled 0.125*log2(e)
    bf16_t* Kb     = ws + 12582912;        // [B,H,S,hd]
    bf16_t* Vb     = ws + 16777216;        // [B,H,hd,S]
    bf16_t* Ob     = ws;                   // [B,S,D]  aliases xb (stream-ordered safe)

    conv_x_kernel<<<2048, 256, 0, stream>>>(x, xb);
    conv_wt_kernel<<<dim3(32, 32, 4), 256, 0, stream>>>(Wq, Wk, Wv, Wo, WqkvT, WoT);
    gemm_qkv_kernel<<<dim3(16, 32), 256, 0, stream>>>(xb, WqkvT, bq, bk, bv, Qb, Kb, Vb);
    attn_kernel<<<512, 256, 0, stream>>>(Qb, Kb, Vb, Ob);
    gemm_o_kernel<<<dim3(16, 64), 128, 0, stream>>>(Ob, WoT, bo, (float*)d_out);
}

// Round 11
// 173.722 us; speedup vs baseline: 1.0379x; 1.0103x over previous
//
#include <hip/hip_runtime.h>
#include <hip/hip_bf16.h>

typedef __bf16 bf16_t;
typedef __bf16 v8bf __attribute__((ext_vector_type(8)));
typedef float  v4f  __attribute__((ext_vector_type(4)));

#define MFMA16(a, b, c) __builtin_amdgcn_mfma_f32_16x16x32_bf16((a), (b), (c), 0, 0, 0)

#define GLDS16(g, l) __builtin_amdgcn_global_load_lds(                         \
    (const __attribute__((address_space(1))) void*)(g),                        \
    (__attribute__((address_space(3))) void*)(l), 16, 0, 0)

// counted-vmcnt sync primitives: raw barrier, no implicit vmcnt(0) drain
#define VMEMCNT(n) asm volatile("s_waitcnt vmcnt(" #n ")" ::: "memory")
#define SBAR()     __builtin_amdgcn_s_barrier()
#define SFENCE()   __builtin_amdgcn_sched_barrier(0)

#define B_SZ   2
#define SEQ    2048
#define DM     1024
#define NH     16
#define HD     64
#define M_TOT  4096

// 0.125 * log2(e): Q pre-scale so softmax uses exp2 with no multiply
#define QSCALE 0.18033688011112043f

// ---------------------------------------------------------------------------
// convert x fp32 -> bf16  (4M elems, 8/thread)
// ---------------------------------------------------------------------------
__global__ __launch_bounds__(256)
void conv_x_kernel(const float* __restrict__ src, bf16_t* __restrict__ dst)
{
    int i = (blockIdx.x * 256 + threadIdx.x) * 8;
    float4 a = *reinterpret_cast<const float4*>(src + i);
    float4 b = *reinterpret_cast<const float4*>(src + i + 4);
    union { bf16_t h[8]; int4 v; } u;
    u.h[0] = (bf16_t)a.x; u.h[1] = (bf16_t)a.y; u.h[2] = (bf16_t)a.z; u.h[3] = (bf16_t)a.w;
    u.h[4] = (bf16_t)b.x; u.h[5] = (bf16_t)b.y; u.h[6] = (bf16_t)b.z; u.h[7] = (bf16_t)b.w;
    *reinterpret_cast<int4*>(dst + i) = u.v;
}

// ---------------------------------------------------------------------------
// transpose+convert W fp32 [k][n] -> bf16 [n][k].  grid (32,32,4)
// ---------------------------------------------------------------------------
__global__ __launch_bounds__(256)
void conv_wt_kernel(const float* __restrict__ Wq, const float* __restrict__ Wk,
                    const float* __restrict__ Wv, const float* __restrict__ Wo,
                    bf16_t* __restrict__ WqkvT, bf16_t* __restrict__ WoT)
{
    __shared__ float t[32][33];
    const int z = blockIdx.z;
    const float* src = (z == 0) ? Wq : (z == 1) ? Wk : (z == 2) ? Wv : Wo;
    bf16_t* dst = (z < 3) ? (WqkvT + (size_t)z * 1048576) : WoT;
    const int tx = threadIdx.x & 31, ty = threadIdx.x >> 5;
    const int c0 = blockIdx.x * 32, r0 = blockIdx.y * 32;
#pragma unroll
    for (int i = 0; i < 4; ++i)
        t[ty + i * 8][tx] = src[(size_t)(r0 + ty + i * 8) * DM + c0 + tx];
    __syncthreads();
#pragma unroll
    for (int i = 0; i < 4; ++i)
        dst[(size_t)(c0 + ty + i * 8) * DM + r0 + tx] = (bf16_t)t[tx][ty + i * 8];
}

// ---------------------------------------------------------------------------
// Fused QKV GEMM.  128x192 tile, dbuf, counted-vmcnt pipeline,
// grid (16,32) = 512 blocks = exactly 2/CU (r12 config, proven fastest).
// ---------------------------------------------------------------------------
__global__ __launch_bounds__(256)
void gemm_qkv_kernel(const bf16_t* __restrict__ A, const bf16_t* __restrict__ BT,
                     const float* __restrict__ b0, const float* __restrict__ b1,
                     const float* __restrict__ b2,
                     bf16_t* __restrict__ oQ, bf16_t* __restrict__ oK,
                     bf16_t* __restrict__ oV)
{
    __shared__ __align__(16) bf16_t As[2 * 128 * 64];   // 32 KB
    __shared__ __align__(16) bf16_t Bs[2 * 192 * 64];   // 48 KB

    const int tid  = threadIdx.x;
    const int lane = tid & 63;
    const int wave = tid >> 6;
    const int wm   = (wave >> 1) * 64;
    const int wn   = (wave & 1) * 96;
    const int quad = lane >> 4;
    const int l15  = lane & 15;
    const int l7   = l15 & 7;

    const int n0 = blockIdx.x * 192;        // flat col in [0,3072)
    const int m0 = blockIdx.y * 128;

    // staging pointers: A 4 loads/thread, B 6 loads/thread (16B each)
    const bf16_t *ap[4], *bp[6];
#pragma unroll
    for (int i = 0; i < 4; ++i) {
        int cidx = (wave * 4 + i) * 64 + lane;          // [0,1024): 128 rows x 8
        int r = cidx >> 3;
        int c = (cidx & 7) ^ (r & 7);
        ap[i] = A + (size_t)(m0 + r) * DM + c * 8;
    }
#pragma unroll
    for (int i = 0; i < 6; ++i) {
        int cidx = (wave * 6 + i) * 64 + lane;          // [0,1536): 192 rows x 8
        int r = cidx >> 3;
        int c = (cidx & 7) ^ (r & 7);
        bp[i] = BT + (size_t)(n0 + r) * DM + c * 8;     // BT flat [3072][1024]
    }

    const v4f vzero = {0.f, 0.f, 0.f, 0.f};
    v4f acc[4][6];
#pragma unroll
    for (int mt = 0; mt < 4; ++mt)
#pragma unroll
        for (int nt = 0; nt < 6; ++nt) acc[mt][nt] = vzero;

    // prologue: tile 0 -> buf 0, tile 1 -> buf 1  (20 loads in flight)
#pragma unroll
    for (int i = 0; i < 4; ++i) { GLDS16(ap[i], As + (wave * 4 + i) * 512); ap[i] += 64; }
#pragma unroll
    for (int i = 0; i < 6; ++i) { GLDS16(bp[i], Bs + (wave * 6 + i) * 512); bp[i] += 64; }
#pragma unroll
    for (int i = 0; i < 4; ++i) { GLDS16(ap[i], As + 8192 + (wave * 4 + i) * 512); ap[i] += 64; }
#pragma unroll
    for (int i = 0; i < 6; ++i) { GLDS16(bp[i], Bs + 12288 + (wave * 6 + i) * 512); bp[i] += 64; }

    for (int it = 0; it < 16; ++it) {
        const int cur = it & 1;
        if (it < 15) { VMEMCNT(10); } else { VMEMCNT(0); }  // tile it complete
        SBAR(); SFENCE();
#pragma unroll
        for (int ks = 0; ks < 2; ++ks) {
            v8bf af[4], bfq[6];
#pragma unroll
            for (int mt = 0; mt < 4; ++mt)
                af[mt] = *reinterpret_cast<const v8bf*>(
                    &As[cur * 8192 + (wm + mt * 16 + l15) * 64 + ((ks * 4 + quad) ^ l7) * 8]);
#pragma unroll
            for (int nt = 0; nt < 6; ++nt)
                bfq[nt] = *reinterpret_cast<const v8bf*>(
                    &Bs[cur * 12288 + (wn + nt * 16 + l15) * 64 + ((ks * 4 + quad) ^ l7) * 8]);
#pragma unroll
            for (int mt = 0; mt < 4; ++mt)
#pragma unroll
                for (int nt = 0; nt < 6; ++nt)
                    acc[mt][nt] = MFMA16(bfq[nt], af[mt], acc[mt][nt]);
        }
        SFENCE(); SBAR();                   // all waves done reading buf cur
        if (it < 14) {                      // stage tile it+2 into buf cur
#pragma unroll
            for (int i = 0; i < 4; ++i) {
                GLDS16(ap[i], As + cur * 8192 + (wave * 4 + i) * 512);
                ap[i] += 64;
            }
#pragma unroll
            for (int i = 0; i < 6; ++i) {
                GLDS16(bp[i], Bs + cur * 12288 + (wave * 6 + i) * 512);
                bp[i] += 64;
            }
        }
    }

    // epilogue: per 16-wide n-frag resolve matrix / head / bias
#pragma unroll
    for (int nt = 0; nt < 6; ++nt) {
        const int cf0 = n0 + wn + nt * 16;      // flat col base of frag
        const int mat = cf0 >> 10;              // 0=Q 1=K 2=V (frag-uniform)
        const int cw  = cf0 & 1023;             // within-matrix col base
        if (mat != 2) {
            bf16_t* dst = (mat == 0) ? oQ : oK;
            const float scale = (mat == 0) ? QSCALE : 1.0f;
            const float* bias = (mat == 0) ? b0 : b1;
            const int h = cw >> 6;
            const int dbase = (cw & 63) + quad * 4;     // 4 contiguous d
            float4 bv = *reinterpret_cast<const float4*>(bias + cw + quad * 4);
#pragma unroll
            for (int mt = 0; mt < 4; ++mt) {
                int srow = m0 + wm + mt * 16 + l15;
                int b = srow >> 11, s = srow & 2047;
                union { bf16_t hh[4]; int2 v; } u;
                u.hh[0] = (bf16_t)((acc[mt][nt][0] + bv.x) * scale);
                u.hh[1] = (bf16_t)((acc[mt][nt][1] + bv.y) * scale);
                u.hh[2] = (bf16_t)((acc[mt][nt][2] + bv.z) * scale);
                u.hh[3] = (bf16_t)((acc[mt][nt][3] + bv.w) * scale);
                *reinterpret_cast<int2*>(
                    dst + ((size_t)(b * NH + h) * SEQ + s) * HD + dbase) = u.v;
            }
        } else {
            // V [B,H,hd,S]: per r fixed d, 16 lanes store contiguous s
#pragma unroll
            for (int r = 0; r < 4; ++r) {
                int cwe = cw + quad * 4 + r;            // h*64+d
                float bvv = b2[cwe];
                int h = cwe >> 6, d = cwe & 63;
#pragma unroll
                for (int mt = 0; mt < 4; ++mt) {
                    int srow = m0 + wm + mt * 16 + l15;
                    int b = srow >> 11, s = srow & 2047;
                    oV[((size_t)(b * NH + h) * HD + d) * SEQ + s] =
                        (bf16_t)(acc[mt][nt][r] + bvv);
                }
            }
        }
    }
}

// ---------------------------------------------------------------------------
// Final projection GEMM.  counted-vmcnt pipeline (6 loads/tile).
// ---------------------------------------------------------------------------
__global__ __launch_bounds__(256)
void gemm_o_kernel(const bf16_t* __restrict__ A, const bf16_t* __restrict__ BT,
                   const float* __restrict__ bias, float* __restrict__ out)
{
    __shared__ __align__(16) bf16_t As[2 * 128 * 64];
    __shared__ __align__(16) bf16_t Bs[2 * 64 * 64];

    const int tid  = threadIdx.x;
    const int lane = tid & 63;
    const int wave = tid >> 6;
    const int wm   = (wave >> 1) * 64;
    const int wn   = (wave & 1) * 32;
    const int quad = lane >> 4;
    const int l15  = lane & 15;
    const int l7   = l15 & 7;

    const int n0 = blockIdx.x * 64;
    const int m0 = blockIdx.y * 128;

    const bf16_t *ap[4], *bp[2];
#pragma unroll
    for (int i = 0; i < 4; ++i) {
        int cidx = (wave * 4 + i) * 64 + lane;
        int r = cidx >> 3;
        int c = (cidx & 7) ^ (r & 7);
        ap[i] = A + (size_t)(m0 + r) * DM + c * 8;
    }
#pragma unroll
    for (int i = 0; i < 2; ++i) {
        int cidx = (wave * 2 + i) * 64 + lane;
        int r = cidx >> 3;
        int c = (cidx & 7) ^ (r & 7);
        bp[i] = BT + (size_t)(n0 + r) * DM + c * 8;
    }

    const v4f vzero = {0.f, 0.f, 0.f, 0.f};
    v4f acc[4][2];
#pragma unroll
    for (int mt = 0; mt < 4; ++mt)
#pragma unroll
        for (int nt = 0; nt < 2; ++nt) acc[mt][nt] = vzero;

    // prologue: tiles 0,1 (12 loads in flight)
#pragma unroll
    for (int i = 0; i < 4; ++i) { GLDS16(ap[i], As + (wave * 4 + i) * 512); ap[i] += 64; }
#pragma unroll
    for (int i = 0; i < 2; ++i) { GLDS16(bp[i], Bs + (wave * 2 + i) * 512); bp[i] += 64; }
#pragma unroll
    for (int i = 0; i < 4; ++i) { GLDS16(ap[i], As + 8192 + (wave * 4 + i) * 512); ap[i] += 64; }
#pragma unroll
    for (int i = 0; i < 2; ++i) { GLDS16(bp[i], Bs + 4096 + (wave * 2 + i) * 512); bp[i] += 64; }

    for (int it = 0; it < 16; ++it) {
        const int cur = it & 1;
        if (it < 15) { VMEMCNT(6); } else { VMEMCNT(0); }
        SBAR(); SFENCE();
#pragma unroll
        for (int ks = 0; ks < 2; ++ks) {
            v8bf af[4], bfq[2];
#pragma unroll
            for (int mt = 0; mt < 4; ++mt)
                af[mt] = *reinterpret_cast<const v8bf*>(
                    &As[cur * 8192 + (wm + mt * 16 + l15) * 64 + ((ks * 4 + quad) ^ l7) * 8]);
#pragma unroll
            for (int nt = 0; nt < 2; ++nt)
                bfq[nt] = *reinterpret_cast<const v8bf*>(
                    &Bs[cur * 4096 + (wn + nt * 16 + l15) * 64 + ((ks * 4 + quad) ^ l7) * 8]);
#pragma unroll
            for (int mt = 0; mt < 4; ++mt)
#pragma unroll
                for (int nt = 0; nt < 2; ++nt)
                    acc[mt][nt] = MFMA16(af[mt], bfq[nt], acc[mt][nt]);
        }
        SFENCE(); SBAR();
        if (it < 14) {
#pragma unroll
            for (int i = 0; i < 4; ++i) {
                GLDS16(ap[i], As + cur * 8192 + (wave * 4 + i) * 512);
                ap[i] += 64;
            }
#pragma unroll
            for (int i = 0; i < 2; ++i) {
                GLDS16(bp[i], Bs + cur * 4096 + (wave * 2 + i) * 512);
                bp[i] += 64;
            }
        }
    }

#pragma unroll
    for (int mt = 0; mt < 4; ++mt) {
#pragma unroll
        for (int nt = 0; nt < 2; ++nt) {
            int col = n0 + wn + nt * 16 + l15;
            float bv = bias[col];
#pragma unroll
            for (int r = 0; r < 4; ++r) {
                int row = m0 + wm + mt * 16 + quad * 4 + r;
                out[(size_t)row * DM + col] = acc[mt][nt][r] + bv;
            }
        }
    }
}

// ---------------------------------------------------------------------------
// Flash attention, causal, static-max softmax (P = exp2(s) directly).
// r15: PAIRED key-tiles on the key-split structure.  Per super-iter a wave
// processes key-tiles (2si, 2si+1):
//   * PV packs BOTH tiles into one K=32 MFMA: k = quad*8+j, j<4 -> tile A
//     key 16w+quad*4+j, j>=4 -> tile B (identical map on the V A-operand,
//     read as 2x b64 from the two buffers).
//   * Barriers per 2 tiles = 2; uniform 17 super-iters/block.
//   * Buffers Ks[4]/Vs[4] (2 pair-slots); ledger: 8 GLDS/pair, prologue
//     stages pairs 0,1; top vmcnt(8) / 0 on last; stage pair si+2 at bottom.
//   * Diag: last super-iter; t even -> diag = tile A, tile B fully masked;
//     t odd -> tile A full, diag = tile B.
//   * Epilogue Ored/lred ALIASED into Ks/Vs (all K/V reads barrier-complete
//     before epilogue writes) -> LDS stays 64KB, 2 blocks/CU.
// XCD remap kept.  Q pre-scaled.  Q,K [B,H,S,hd]; V [B,H,hd,S]; O [B,S,D].
// ---------------------------------------------------------------------------
__global__ __launch_bounds__(256)
void attn_kernel(const bf16_t* __restrict__ Q, const bf16_t* __restrict__ K,
                 const bf16_t* __restrict__ Vt, bf16_t* __restrict__ O)
{
    __shared__ __align__(16) bf16_t Ks[4][64 * 64];
    __shared__ __align__(16) bf16_t Vs[4][64 * 64];
    float* Ored = reinterpret_cast<float*>(&Ks[0][0]);   // 16.6KB alias (post-loop)
    float* lred = reinterpret_cast<float*>(&Vs[0][0]);   // 1KB alias (post-loop)

    const int tid  = threadIdx.x;
    const int lane = tid & 63;
    const int w    = tid >> 6;
    const int quad = lane >> 4;
    const int l15  = lane & 15;
    const int l7   = lane & 7;

    const int bid = blockIdx.x;             // 0..511
    const int xcd = bid & 7;
    const int j   = bid >> 3;               // 0..63
    const int bh  = (xcd << 2) | (j >> 4);  // 4 bh per XCD
    const int p   = j & 15;                 // pair index 0..15
    const size_t base = (size_t)bh * SEQ * HD;
    const bf16_t* Qg = Q  + base;
    const bf16_t* Kg = K  + base;
    const bf16_t* Vg = Vt + base;

    // staging: thread covers rows rr0 and rr0+32, source pre-swizzled col cc0
    const int rr0 = tid >> 3;
    const int cc0 = (tid & 7) ^ (rr0 & 7);
    const int bO = bh >> 4, hO = bh & 15;
    const v4f vzero = {0.f, 0.f, 0.f, 0.f};

    for (int phase = 0; phase < 2; ++phase) {
        const int t  = phase ? (31 - p) : p;   // q-tile index; t0 + t1 = 31
        const int q0 = t * 64;
        const int ns = (t + 2) >> 1;           // super-iters (key-tile pairs)
        const bool tEven = ((t & 1) == 0);

        // ALL 64 q rows in registers: qf[g][ks], g = q-group (16 rows each)
        v8bf qf[4][2];
#pragma unroll
        for (int g = 0; g < 4; ++g) {
            const bf16_t* qrow = Qg + (size_t)(q0 + g * 16 + l15) * HD;
            qf[g][0] = *reinterpret_cast<const v8bf*>(qrow + quad * 8);
            qf[g][1] = *reinterpret_cast<const v8bf*>(qrow + 32 + quad * 8);
        }

        const bf16_t* kp0 = Kg + (size_t)rr0 * HD + cc0 * 8;
        const bf16_t* kp1 = kp0 + 32 * HD;
        const bf16_t* vp0 = Vg + (size_t)rr0 * SEQ + cc0 * 8;
        const bf16_t* vp1 = vp0 + (size_t)32 * SEQ;

        v4f acc_p[4][4];                    // [d-tile][q-group] partial O^T
#pragma unroll
        for (int dt = 0; dt < 4; ++dt)
#pragma unroll
            for (int g = 0; g < 4; ++g) acc_p[dt][g] = vzero;
        float lp[4] = {0.f, 0.f, 0.f, 0.f}; // per-lane l partials per q-group

        // drain qf loads (and prev-phase epilogue stores) -> GLDS-only ledger
        VMEMCNT(0);
        SBAR();              // prev phase's epilogue LDS readers done

        // prologue: pair 0 -> slots 0,1; pair 1 -> slots 2,3 (8 GLDS each)
#pragma unroll
        for (int s = 0; s < 2; ++s) {
            GLDS16(kp0, &Ks[s][w * 512]);  GLDS16(kp1, &Ks[s][2048 + w * 512]);
            GLDS16(vp0, &Vs[s][w * 512]);  GLDS16(vp1, &Vs[s][2048 + w * 512]);
            kp0 += 64 * HD;  kp1 += 64 * HD;  vp0 += 64;  vp1 += 64;
        }
        if (ns > 1) {
#pragma unroll
            for (int s = 2; s < 4; ++s) {
                GLDS16(kp0, &Ks[s][w * 512]);  GLDS16(kp1, &Ks[s][2048 + w * 512]);
                GLDS16(vp0, &Vs[s][w * 512]);  GLDS16(vp1, &Vs[s][2048 + w * 512]);
                kp0 += 64 * HD;  kp1 += 64 * HD;  vp0 += 64;  vp1 += 64;
            }
        }

        for (int si = 0; si < ns; ++si) {
            const int sA = (si & 1) * 2, sB = sA + 1;
            if (si + 1 < ns) { VMEMCNT(8); } else { VMEMCNT(0); }  // pair si done
            SBAR(); SFENCE();

            const bool last  = (si == ns - 1);
            const bool diagA = last && tEven;     // also: tile B fully masked
            const bool diagB = last && !tEven;

            // S^T on this wave's 16-key slice, tiles A and B
            v4f stA[4], stB[4];
#pragma unroll
            for (int g = 0; g < 4; ++g) { stA[g] = vzero; stB[g] = vzero; }
#pragma unroll
            for (int ks = 0; ks < 2; ++ks) {
                const int koff = (16 * w + l15) * 64 + ((ks * 4 + quad) ^ l7) * 8;
                v8bf kfA = *reinterpret_cast<const v8bf*>(&Ks[sA][koff]);
                v8bf kfB = *reinterpret_cast<const v8bf*>(&Ks[sB][koff]);
#pragma unroll
                for (int g = 0; g < 4; ++g) {
                    stA[g] = MFMA16(kfA, qf[g][ks], stA[g]);
                    stB[g] = MFMA16(kfB, qf[g][ks], stB[g]);
                }
            }
            // stX[g][r] = S[key = 16w + quad*4 + r (of tile X)][q = g*16 + l15]

            // softmax (static-max): pack BOTH tiles into one k=32 B-frag:
            // k = quad*8+j: j<4 -> tile A key 16w+quad*4+j; j>=4 -> tile B
            v8bf pa[4];
#pragma unroll
            for (int g = 0; g < 4; ++g) {
                union { bf16_t h[8]; v8bf v; } up;
                // tile A half (j = 0..3)
                if (diagA && g < w) {
                    up.h[0] = (bf16_t)0.f; up.h[1] = (bf16_t)0.f;
                    up.h[2] = (bf16_t)0.f; up.h[3] = (bf16_t)0.f;
                } else if (diagA && g == w) {
#pragma unroll
                    for (int r = 0; r < 4; ++r) {
                        float pv = (quad * 4 + r > l15)
                                     ? 0.f : __builtin_amdgcn_exp2f(stA[g][r]);
                        lp[g] += pv;
                        up.h[r] = (bf16_t)pv;
                    }
                } else {
#pragma unroll
                    for (int r = 0; r < 4; ++r) {
                        float pv = __builtin_amdgcn_exp2f(stA[g][r]);
                        lp[g] += pv;
                        up.h[r] = (bf16_t)pv;
                    }
                }
                // tile B half (j = 4..7); diagA implies B fully masked
                if (diagA || (diagB && g < w)) {
                    up.h[4] = (bf16_t)0.f; up.h[5] = (bf16_t)0.f;
                    up.h[6] = (bf16_t)0.f; up.h[7] = (bf16_t)0.f;
                } else if (diagB && g == w) {
#pragma unroll
                    for (int r = 0; r < 4; ++r) {
                        float pv = (quad * 4 + r > l15)
                                     ? 0.f : __builtin_amdgcn_exp2f(stB[g][r]);
                        lp[g] += pv;
                        up.h[4 + r] = (bf16_t)pv;
                    }
                } else {
#pragma unroll
                    for (int r = 0; r < 4; ++r) {
                        float pv = __builtin_amdgcn_exp2f(stB[g][r]);
                        lp[g] += pv;
                        up.h[4 + r] = (bf16_t)pv;
                    }
                }
                pa[g] = up.v;
            }

            // O^T_partial += V^T P  (full k=32: tile A keys j<4, tile B j>=4)
#pragma unroll
            for (int dt = 0; dt < 4; ++dt) {
                const int rowd = dt * 16 + l15;
                const int voff = rowd * 64 +
                    (((2 * w + (quad >> 1)) ^ l7) * 8 + (quad & 1) * 4);
                uint2 va = *reinterpret_cast<const uint2*>(&Vs[sA][voff]);
                uint2 vb = *reinterpret_cast<const uint2*>(&Vs[sB][voff]);
                union { unsigned u[4]; v8bf v; } uv;
                uv.u[0] = va.x; uv.u[1] = va.y; uv.u[2] = vb.x; uv.u[3] = vb.y;
#pragma unroll
                for (int g = 0; g < 4; ++g)
                    acc_p[dt][g] = MFMA16(uv.v, pa[g], acc_p[dt][g]);
            }

            SFENCE(); SBAR();               // all waves done with pair si
            if (si + 2 < ns) {              // stage pair si+2 into slots sA,sB
                GLDS16(kp0, &Ks[sA][w * 512]);  GLDS16(kp1, &Ks[sA][2048 + w * 512]);
                GLDS16(vp0, &Vs[sA][w * 512]);  GLDS16(vp1, &Vs[sA][2048 + w * 512]);
                kp0 += 64 * HD;  kp1 += 64 * HD;  vp0 += 64;  vp1 += 64;
                GLDS16(kp0, &Ks[sB][w * 512]);  GLDS16(kp1, &Ks[sB][2048 + w * 512]);
                GLDS16(vp0, &Vs[sB][w * 512]);  GLDS16(vp1, &Vs[sB][2048 + w * 512]);
                kp0 += 64 * HD;  kp1 += 64 * HD;  vp0 += 64;  vp1 += 64;
            }
        }

        // ---- phase epilogue: cross-wave reduction of O partials and l ----
        // (Ored/lred alias Ks/Vs: all K/V reads completed at last bottom SBAR)
#pragma unroll
        for (int g = 0; g < 4; ++g) {
            lp[g] += __shfl_xor(lp[g], 16);
            lp[g] += __shfl_xor(lp[g], 32);
        }
        if (quad == 0) {
#pragma unroll
            for (int g = 0; g < 4; ++g)
                lred[w * 64 + g * 16 + l15] = lp[g];
        }

        const int qq = tid >> 2;            // q within tile, 0..63
        const int db = (tid & 3) * 4;       // d-quad within 16-d tile
        float linv = 0.f;
#pragma unroll
        for (int dt = 0; dt < 4; ++dt) {
            // each wave writes its partial for this 16-d tile (stride-65 pad)
#pragma unroll
            for (int g = 0; g < 4; ++g)
#pragma unroll
                for (int r = 0; r < 4; ++r)
                    Ored[w * 1040 + (quad * 4 + r) * 65 + g * 16 + l15] =
                        acc_p[dt][g][r];
            SBAR();
            if (dt == 0)
                linv = 1.f / (lred[qq] + lred[64 + qq] +
                              lred[128 + qq] + lred[192 + qq]);
            union { bf16_t h[4]; int2 v; } u;
#pragma unroll
            for (int e = 0; e < 4; ++e) {
                float s = Ored[(db + e) * 65 + qq]
                        + Ored[1040 + (db + e) * 65 + qq]
                        + Ored[2080 + (db + e) * 65 + qq]
                        + Ored[3120 + (db + e) * 65 + qq];
                u.h[e] = (bf16_t)(s * linv);
            }
            *reinterpret_cast<int2*>(
                &O[((size_t)bO * SEQ + q0 + qq) * DM + hO * 64 + dt * 16 + db]) = u.v;
            SBAR();                         // reads done before next round
        }
    }
}

// ---------------------------------------------------------------------------
extern "C" void kernel_launch(void* const* d_in, const int* in_sizes, int n_in,
                              void* d_out, int out_size, void* d_ws, size_t ws_size,
                              hipStream_t stream) {
    const float* x  = (const float*)d_in[0];
    const float* Wq = (const float*)d_in[1];
    const float* bq = (const float*)d_in[2];
    const float* Wk = (const float*)d_in[3];
    const float* bk = (const float*)d_in[4];
    const float* Wv = (const float*)d_in[5];
    const float* bv = (const float*)d_in[6];
    const float* Wo = (const float*)d_in[7];
    const float* bo = (const float*)d_in[8];

    bf16_t* ws = (bf16_t*)d_ws;
    bf16_t* xb     = ws;                   // [4096,1024]        4M  (dead after QKV)
    bf16_t* WqkvT  = ws + 4194304;         // [3,1024n,1024k]    3M (flat [3072][1024])
    bf16_t* WoT    = ws + 7340032;         // [1024n,1024k]      1M
    bf16_t* Qb     = ws + 8388608;         // [B,H,S,hd]  pre-scaled 0.125*log2(e)
    bf16_t* Kb     = ws + 12582912;        // [B,H,S,hd]
    bf16_t* Vb     = ws + 16777216;        // [B,H,hd,S]
    bf16_t* Ob     = ws;                   // [B,S,D]  aliases xb (stream-ordered safe)

    conv_x_kernel<<<2048, 256, 0, stream>>>(x, xb);
    conv_wt_kernel<<<dim3(32, 32, 4), 256, 0, stream>>>(Wq, Wk, Wv, Wo, WqkvT, WoT);
    gemm_qkv_kernel<<<dim3(16, 32), 256, 0, stream>>>(xb, WqkvT, bq, bk, bv, Qb, Kb, Vb);
    attn_kernel<<<512, 256, 0, stream>>>(Qb, Kb, Vb, Ob);
    gemm_o_kernel<<<dim3(16, 32), 256, 0, stream>>>(Ob, WoT, bo, (float*)d_out);
}